// Round 13
// baseline (107.842 us; speedup 1.0000x reference)
//
#include <hip/hip_runtime.h>

// out[b,c] = logsumexp_d(x[b,d] + log_softmax(weight)[c,d])
//          = log( sum_d exp(x[b,d]) * softmax(weight)[c,d] )
// x:[8192,2048] f32, weight:[10,2048] f32
constexpr int B = 8192;
constexpr int D = 2048;   // P*N
constexpr int C = 10;
constexpr int D4 = D / 4;   // 512 float4 per row
constexpr int HD4 = D4 / 2; // 256 float4 per half-row

// ---------------- Kernel 1: p[c,:] = softmax(weight[c,:]) ----------------
__global__ __launch_bounds__(256) void softmax_w_kernel(
    const float* __restrict__ w, float* __restrict__ p) {
  const int c = blockIdx.x;
  const int t = threadIdx.x;          // 0..255
  const int lane = t & 63, wid = t >> 6;

  const float4* wr = reinterpret_cast<const float4*>(w + c * D);
  float4 v0 = wr[t];
  float4 v1 = wr[t + 256];

  float m = fmaxf(fmaxf(fmaxf(v0.x, v0.y), fmaxf(v0.z, v0.w)),
                  fmaxf(fmaxf(v1.x, v1.y), fmaxf(v1.z, v1.w)));
#pragma unroll
  for (int o = 1; o < 64; o <<= 1) m = fmaxf(m, __shfl_xor(m, o));
  __shared__ float sred[4];
  if (lane == 0) sred[wid] = m;
  __syncthreads();
  m = fmaxf(fmaxf(sred[0], sred[1]), fmaxf(sred[2], sred[3]));
  __syncthreads();

  float4 e0, e1;
  e0.x = __expf(v0.x - m); e0.y = __expf(v0.y - m);
  e0.z = __expf(v0.z - m); e0.w = __expf(v0.w - m);
  e1.x = __expf(v1.x - m); e1.y = __expf(v1.y - m);
  e1.z = __expf(v1.z - m); e1.w = __expf(v1.w - m);

  float s = (e0.x + e0.y + e0.z + e0.w) + (e1.x + e1.y + e1.z + e1.w);
#pragma unroll
  for (int o = 1; o < 64; o <<= 1) s += __shfl_xor(s, o);
  if (lane == 0) sred[wid] = s;
  __syncthreads();
  s = (sred[0] + sred[1]) + (sred[2] + sred[3]);

  const float inv = 1.0f / s;
  float4 q0 = {e0.x * inv, e0.y * inv, e0.z * inv, e0.w * inv};
  float4 q1 = {e1.x * inv, e1.y * inv, e1.z * inv, e1.w * inv};
  float4* pr = reinterpret_cast<float4*>(p + c * D);
  pr[t] = q0;
  pr[t + 256] = q1;
}

// ---------------- Kernel 2 ----------------
// 1024 threads = 16 waves/block; block owns 16 rows, D split across halves:
// wave w: half h = w>>3 (d in [h*1024,(h+1)*1024)), rows 2*(w&7), +1.
// grid = B/16 = 512 blocks -> 8192 waves = 32 waves/CU (2 blocks/CU @ 80KB
// LDS, 2048 thr/CU). R6->R9 showed time ~ 1/waves (latency-bound on the
// ds_read+FMA chain); this doubles waves/SIMD 4 -> 8 at UNCHANGED total LDS
// traffic (each wave reads 40KB of p per 2 rows; 335 MB total).
// VGPR must stay <=64 for 8 waves/SIMD: rolled loop, live set ~55.
// Partials combined in-block via the dead p-buffer (aliased after barrier).
__global__ __launch_bounds__(1024, 8) void lse_main_kernel(
    const float* __restrict__ x, const float* __restrict__ p,
    float* __restrict__ out) {
  __shared__ float4 plds[C * D4];   // 80 KB, [c][f4 0..511]

  const int t = threadIdx.x;        // 0..1023
  const int lane = t & 63, w = t >> 6;   // w 0..15

  // stage full p -> LDS: 5120 float4 / 1024 threads = 5 each, coalesced
#pragma unroll
  for (int k = 0; k < 5; ++k)
    plds[k * 1024 + t] = reinterpret_cast<const float4*>(p)[k * 1024 + t];
  __syncthreads();

  const int h = w >> 3;                       // D-half
  const int rp = w & 7;                       // row pair within block
  const int row0 = blockIdx.x * 16 + rp * 2;  // 2 rows per wave
  const int base = h * HD4;                   // f4 offset of this half
  const float4* xr = reinterpret_cast<const float4*>(x + (size_t)row0 * D);

  float acc0[C], acc1[C];
#pragma unroll
  for (int c = 0; c < C; ++c) { acc0[c] = 0.0f; acc1[c] = 0.0f; }

  float4 nx0 = xr[base + lane];
  float4 nx1 = xr[D4 + base + lane];

#pragma unroll 1
  for (int j = 0; j < 4; ++j) {
    const float4 cx0 = nx0, cx1 = nx1;
    const int fn = base + ((j + 1) & 3) * 64 + lane;  // wraps, in-bounds
    nx0 = xr[fn];
    nx1 = xr[D4 + fn];

    float4 e0, e1;
    e0.x = __expf(cx0.x); e0.y = __expf(cx0.y);
    e0.z = __expf(cx0.z); e0.w = __expf(cx0.w);
    e1.x = __expf(cx1.x); e1.y = __expf(cx1.y);
    e1.z = __expf(cx1.z); e1.w = __expf(cx1.w);

    const int f4i = base + j * 64 + lane;
#pragma unroll
    for (int c = 0; c < C; ++c) {
      const float4 pv = plds[c * D4 + f4i];
      acc0[c] += e0.x * pv.x + e0.y * pv.y + e0.z * pv.z + e0.w * pv.w;
      acc1[c] += e1.x * pv.x + e1.y * pv.y + e1.z * pv.z + e1.w * pv.w;
    }
  }

  // main-loop plds reads complete for ALL waves before aliasing the buffer
  __syncthreads();

  // part[row 0..15][c 0..9][half 0..1] aliased onto dead plds memory (1.3KB)
  float* part = reinterpret_cast<float*>(plds);

  // wave butterfly reduction; lane c writes its half-partial for both rows
#pragma unroll
  for (int c = 0; c < C; ++c) {
    float v0 = acc0[c], v1 = acc1[c];
#pragma unroll
    for (int o = 1; o < 64; o <<= 1) {
      v0 += __shfl_xor(v0, o);
      v1 += __shfl_xor(v1, o);
    }
    if (lane == c) {
      part[((rp * 2 + 0) * C + c) * 2 + h] = v0;
      part[((rp * 2 + 1) * C + c) * 2 + h] = v1;
    }
  }
  __syncthreads();

  // combine halves + log + store: 160 outputs per block
  if (t < 16 * C) {
    const int row = t / C, c = t % C;
    const float s = part[(row * C + c) * 2] + part[(row * C + c) * 2 + 1];
    out[(size_t)(blockIdx.x * 16 + row) * C + c] = logf(s);
  }
}

extern "C" void kernel_launch(void* const* d_in, const int* in_sizes, int n_in,
                              void* d_out, int out_size, void* d_ws, size_t ws_size,
                              hipStream_t stream) {
  const float* x = (const float*)d_in[0];       // [B, D]
  const float* w = (const float*)d_in[1];       // [C, D]
  float* out = (float*)d_out;                   // [B, C]
  float* p = (float*)d_ws;                      // [C, D] scratch (80 KB)

  softmax_w_kernel<<<C, 256, 0, stream>>>(w, p);
  lse_main_kernel<<<B / 16, 1024, 0, stream>>>(x, p, out);
}

// Round 15
// 95.731 us; speedup vs baseline: 1.1265x; 1.1265x over previous
//
#include <hip/hip_runtime.h>

// out[b,c] = logsumexp_d(x[b,d] + log_softmax(weight)[c,d])
//          = log( exp(x[b,:]) . softmax(weight)[c,:] )
// GEMM form: E[8192x2048] (f16) @ P16^T[2048x16] (f16, rows 10..15 zero),
// accumulated f32 via mfma_f32_16x16x32_f16. P16 scaled by 1024 to stay in
// f16 normal range; epilogue subtracts log(1024).
constexpr int B = 8192;
constexpr int D = 2048;   // P*N
constexpr int C = 10;
constexpr int CP = 16;    // padded classes

typedef _Float16 f16x8 __attribute__((ext_vector_type(8)));
typedef float f32x4 __attribute__((ext_vector_type(4)));

// ---------------- Kernel 1: p16[c,:] = 1024 * softmax(weight[c,:]) as f16 ----
__global__ __launch_bounds__(256) void softmax_w16(
    const float* __restrict__ w, _Float16* __restrict__ p16) {
  const int c = blockIdx.x;           // 0..15
  const int t = threadIdx.x;          // 0..255
  union H4 { _Float16 h[4]; uint2 u; };

  if (c >= C) {                       // zero-pad rows 10..15 (ws is poisoned!)
    H4 z; z.u = make_uint2(0u, 0u);
    *reinterpret_cast<uint2*>(p16 + c * D + 4 * t) = z.u;
    *reinterpret_cast<uint2*>(p16 + c * D + 1024 + 4 * t) = z.u;
    return;
  }

  const int lane = t & 63, wid = t >> 6;
  const float4* wr = reinterpret_cast<const float4*>(w + c * D);
  float4 v0 = wr[t];          // d = 4t..4t+3
  float4 v1 = wr[t + 256];    // d = 1024+4t..

  float m = fmaxf(fmaxf(fmaxf(v0.x, v0.y), fmaxf(v0.z, v0.w)),
                  fmaxf(fmaxf(v1.x, v1.y), fmaxf(v1.z, v1.w)));
#pragma unroll
  for (int o = 1; o < 64; o <<= 1) m = fmaxf(m, __shfl_xor(m, o));
  __shared__ float sred[4];
  if (lane == 0) sred[wid] = m;
  __syncthreads();
  m = fmaxf(fmaxf(sred[0], sred[1]), fmaxf(sred[2], sred[3]));
  __syncthreads();

  float4 e0, e1;
  e0.x = __expf(v0.x - m); e0.y = __expf(v0.y - m);
  e0.z = __expf(v0.z - m); e0.w = __expf(v0.w - m);
  e1.x = __expf(v1.x - m); e1.y = __expf(v1.y - m);
  e1.z = __expf(v1.z - m); e1.w = __expf(v1.w - m);

  float s = (e0.x + e0.y + e0.z + e0.w) + (e1.x + e1.y + e1.z + e1.w);
#pragma unroll
  for (int o = 1; o < 64; o <<= 1) s += __shfl_xor(s, o);
  if (lane == 0) sred[wid] = s;
  __syncthreads();
  s = (sred[0] + sred[1]) + (sred[2] + sred[3]);

  const float inv = 1024.0f / s;      // scale keeps f16 values normal
  H4 a, b2;
  a.h[0]  = (_Float16)(e0.x * inv); a.h[1]  = (_Float16)(e0.y * inv);
  a.h[2]  = (_Float16)(e0.z * inv); a.h[3]  = (_Float16)(e0.w * inv);
  b2.h[0] = (_Float16)(e1.x * inv); b2.h[1] = (_Float16)(e1.y * inv);
  b2.h[2] = (_Float16)(e1.z * inv); b2.h[3] = (_Float16)(e1.w * inv);
  *reinterpret_cast<uint2*>(p16 + c * D + 4 * t) = a.u;
  *reinterpret_cast<uint2*>(p16 + c * D + 1024 + 4 * t) = b2.u;
}

// ---------------- Kernel 2: MFMA GEMM + log ----------------
// 512 thr = 8 waves; block owns 16 rows. Stage exp(x)->f16 into 64 KB LDS
// (XOR swizzle: elem ^= (row&7)<<3 i.e. byte ^= (row&7)<<4). Wave w owns
// k in [w*256,(w+1)*256): 8 x mfma_f32_16x16x32_f16 vs B-frags preloaded
// from global p16 (L3-resident, 33 MB total re-reads). Partials summed in
// LDS. Grid 512 blocks -> 2 blocks/CU (LDS-capped), 16 waves/CU.
__global__ __launch_bounds__(512) void lse_mfma(
    const float* __restrict__ x, const _Float16* __restrict__ p16,
    float* __restrict__ out) {
  __shared__ __align__(16) _Float16 e16[16 * D];   // 64 KB

  const int t = threadIdx.x;       // 0..511
  const int lane = t & 63;
  const int w = t >> 6;            // wave 0..7

  // --- B-fragment preload (consumed after barrier; hides under staging) ---
  // B[k][n]: lane l -> col c = l&15, k = kchunk + s*32 + (l>>4)*8 + 0..7
  const int ccol = lane & 15;
  const int ksub = (lane >> 4) * 8;
  f16x8 bf[8];
#pragma unroll
  for (int s = 0; s < 8; ++s)
    bf[s] = *reinterpret_cast<const f16x8*>(p16 + ccol * D + w * 256 + s * 32 + ksub);

  // --- stage exp(x) tile: thread t -> row t>>5, kc = t&31; k = kc*4 + j*128 ---
  const int srow = t >> 5, kc = t & 31;
  const float4* xr =
      reinterpret_cast<const float4*>(x + ((size_t)blockIdx.x * 16 + srow) * D);
#pragma unroll 4
  for (int j = 0; j < 16; ++j) {
    const int kk = kc * 4 + j * 128;
    const float4 v = xr[kk >> 2];                 // coalesced 512B/row-group
    union { _Float16 h[4]; uint2 u; } pk;
    pk.h[0] = (_Float16)__expf(v.x);
    pk.h[1] = (_Float16)__expf(v.y);
    pk.h[2] = (_Float16)__expf(v.z);
    pk.h[3] = (_Float16)__expf(v.w);
    const int sidx = (srow * D + kk) ^ ((srow & 7) << 3);   // swizzled store
    *reinterpret_cast<uint2*>(&e16[sidx]) = pk.u;
  }
  __syncthreads();

  // --- MFMA k-loop: A[row][k] = e16(row, k), lane l -> row l&15, k += (l>>4)*8 ---
  const int arow = lane & 15;
  f32x4 acc = {0.f, 0.f, 0.f, 0.f};
#pragma unroll
  for (int s = 0; s < 8; ++s) {
    const int kbase = w * 256 + s * 32 + ksub;
    const int ridx = (arow * D + kbase) ^ ((arow & 7) << 3);
    const f16x8 a = *reinterpret_cast<const f16x8*>(&e16[ridx]);
    acc = __builtin_amdgcn_mfma_f32_16x16x32_f16(a, bf[s], acc, 0, 0, 0);
  }
  __syncthreads();   // all waves done reading e16 before aliasing

  // --- partial sum across waves via LDS (C/D: col=lane&15, row=(lane>>4)*4+r) ---
  float* part = reinterpret_cast<float*>(e16);   // 8 waves * 256 f32 = 8 KB
#pragma unroll
  for (int r = 0; r < 4; ++r)
    part[w * 256 + ((lane >> 4) * 4 + r) * 16 + (lane & 15)] = acc[r];
  __syncthreads();

  if (t < 256) {
    const int col = t & 15;
    float s = 0.f;
#pragma unroll
    for (int w2 = 0; w2 < 8; ++w2) s += part[w2 * 256 + t];
    if (col < C) {
      const int row = t >> 4;
      // undo the 1024x p-scale: log(s/1024) = log(s) - log(1024)
      out[((size_t)blockIdx.x * 16 + row) * C + col] =
          logf(s) - 6.931471805599453f;
    }
  }
}

extern "C" void kernel_launch(void* const* d_in, const int* in_sizes, int n_in,
                              void* d_out, int out_size, void* d_ws, size_t ws_size,
                              hipStream_t stream) {
  const float* x = (const float*)d_in[0];       // [B, D]
  const float* w = (const float*)d_in[1];       // [C, D]
  float* out = (float*)d_out;                   // [B, C]
  _Float16* p16 = (_Float16*)d_ws;              // [CP, D] f16 scratch (64 KB)

  softmax_w16<<<CP, 256, 0, stream>>>(w, p16);
  lse_mfma<<<B / 16, 512, 0, stream>>>(x, p16, out);
}